// Round 11
// baseline (3121.010 us; speedup 1.0000x reference)
//
#include <hip/hip_runtime.h>
#include <cmath>
#include <cstdint>

#define NWG 256
#define NT  256

// dims: B=16, T=64, L=64, D=512, A=256, 4D=2048
// ws float offsets
#define WS_FLAGS 0         // u32 flags[256][16]: w0 = gsync (16 KB)
#define WS_HC    8192      // 16*512   (h_ctx, rewritten per step; bypass-only)
#define WS_CT    16384     // 16*64*256 ctx_trans (write-once prologue, cached reads)
#define WS_CACHE 278528    // 16*64*256 hist proj rows (same-WG write+read, plain cached)
#define WS_HIST  540672    // 16*64*512 h history rows (write-once per row; bypass write / cached reads)
#define WS_HHP   1064960   // u32 [col=256][k=512]: packed (bf16 hthW1 | bf16 hhW<<16) (write-once)
#define WS_AHB   1196032   // u32 [col=256][kk=256]: bf16 ahW1 k-pairs (write-once)
// end: 1261568 floats = 4.82 MB

// out float offsets (hs | cs | ctxs)
#define OUT_HS  0
#define OUT_CS  524288
#define OUT_CTX 1048576

// lds float offsets
#define LDS_WT   0        // 4 quarters x 5140 (2560 K rows * 2 cols interleaved + pad; 5140%32=20 -> cp banks distinct)
#define LDS_ZS   20560    // z-stage [16 b][516]
#define LDS_SCR  28816    // scratch 2048 (gemm reduce / einsum partials / prologue)
#define LDS_GLD  30864    // g lds 16*8
#define LDS_ATT  30992    // aw 256 | av2 256 | abv 256 | araw 64 | asmx 64 | arawZ 64 | hst 512
#define LDS_FLOATS 32464  // *4 = 129,856 B < 160 KB

typedef float vf4 __attribute__((ext_vector_type(4)));
typedef float vf2 __attribute__((ext_vector_type(2)));
typedef uint32_t vu4 __attribute__((ext_vector_type(4)));

struct CAParams {
  const float* X; const float* ctx; const int* parent; const int* cmask; const float* mask;
  const float* Wx; const float* bx; const float* U; const float* C; const float* P; const float* H;
  const float* acW1; const float* ab1; const float* ahW1; const float* aW2; const float* ab2;
  const float* hhW; const float* hhb; const float* hthW1; const float* hW2; const float* hb2;
  float* out; float* ws;
};

__device__ __forceinline__ float tanh_f(float x) {
  x = fminf(15.f, fmaxf(-15.f, x));
  float e = __expf(2.f * x);
  return (e - 1.f) / (e + 1.f);
}
__device__ __forceinline__ float sigm_f(float x) { return 1.f / (1.f + __expf(-x)); }
__device__ __forceinline__ float wsum(float v) {
  #pragma unroll
  for (int m = 32; m; m >>= 1) v += __shfl_xor(v, m, 64);
  return v;
}
__device__ __forceinline__ float wmax(float v) {
  #pragma unroll
  for (int m = 32; m; m >>= 1) v = fmaxf(v, __shfl_xor(v, m, 64));
  return v;
}
__device__ __forceinline__ float hsum32(float v) {  // reduce within 32-lane half
  #pragma unroll
  for (int m = 16; m; m >>= 1) v += __shfl_xor(v, m, 64);
  return v;
}
// bf16 round-to-nearest-even
__device__ __forceinline__ uint32_t f2bf(float f) {
  uint32_t u = __float_as_uint(f);
  return (u + 0x7FFFu + ((u >> 16) & 1u)) >> 16;
}
__device__ __forceinline__ float bflo(uint32_t pk) { return __uint_as_float(pk << 16); }
__device__ __forceinline__ float bfhi(uint32_t pk) { return __uint_as_float(pk & 0xFFFF0000u); }

// ---- MALL-coherent bypass ops (sc0 sc1), non-atomic so they pipeline ----
__device__ __forceinline__ void bst(float* a, float v) {
  asm volatile("global_store_dword %0, %1, off sc0 sc1" :: "v"(a), "v"(v) : "memory");
}
__device__ __forceinline__ void bstu(uint32_t* a, uint32_t v) {
  asm volatile("global_store_dword %0, %1, off sc0 sc1" :: "v"(a), "v"(v) : "memory");
}
__device__ __forceinline__ void bst4(float* a, vf4 v) {
  asm volatile("global_store_dwordx4 %0, %1, off sc0 sc1" :: "v"(a), "v"(v) : "memory");
}
// issue-only 8-deep bypass loads; pair with bwait8 (data-dep via +v prevents hoisting)
__device__ __forceinline__ void bld8_issue(vf4* r, const float* q0, const float* q1, const float* q2, const float* q3,
                                           const float* q4, const float* q5, const float* q6, const float* q7) {
  asm volatile(
    "global_load_dwordx4 %0, %8, off sc0 sc1\n"
    "global_load_dwordx4 %1, %9, off sc0 sc1\n"
    "global_load_dwordx4 %2, %10, off sc0 sc1\n"
    "global_load_dwordx4 %3, %11, off sc0 sc1\n"
    "global_load_dwordx4 %4, %12, off sc0 sc1\n"
    "global_load_dwordx4 %5, %13, off sc0 sc1\n"
    "global_load_dwordx4 %6, %14, off sc0 sc1\n"
    "global_load_dwordx4 %7, %15, off sc0 sc1"
    : "=&v"(r[0]),"=&v"(r[1]),"=&v"(r[2]),"=&v"(r[3]),"=&v"(r[4]),"=&v"(r[5]),"=&v"(r[6]),"=&v"(r[7])
    : "v"(q0),"v"(q1),"v"(q2),"v"(q3),"v"(q4),"v"(q5),"v"(q6),"v"(q7)
    : "memory");
}
__device__ __forceinline__ void bwait8(vf4* r) {
  asm volatile("s_waitcnt vmcnt(0)"
    : "+v"(r[0]),"+v"(r[1]),"+v"(r[2]),"+v"(r[3]),"+v"(r[4]),"+v"(r[5]),"+v"(r[6]),"+v"(r[7])
    :: "memory");
}

__global__ void __launch_bounds__(NT, 1) condatt_kernel(CAParams p) {
  extern __shared__ float lds[];
  float* wt   = lds + LDS_WT;
  float* zs   = lds + LDS_ZS;
  float* scr  = lds + LDS_SCR;
  float* gld  = lds + LDS_GLD;
  float* aw   = lds + LDS_ATT;
  float* av2  = lds + LDS_ATT + 256;
  float* abv  = lds + LDS_ATT + 512;
  float* araw = lds + LDS_ATT + 768;
  float* asmx = lds + LDS_ATT + 832;
  float* arawZ= lds + LDS_ATT + 896;
  float* hst  = lds + LDS_ATT + 960;   // 512

  const int tid = threadIdx.x;
  const int wg  = blockIdx.x;
  float* wsp = p.ws;
  unsigned* flags = (unsigned*)wsp;    // 64B-strided flags, one line per WG
  unsigned nbar = 0;

  // XCD-contiguous column assignment (wg%8 = XCD)
  const int base = 2 * ((wg & 7) * 32 + (wg >> 3));  // gate col pair {base, base+1}

  // discard stale L1/L2 lines from previous dispatch/poison blit
  __threadfence_system();

  const int kh = tid >> 4, sub = tid & 15, bg = sub >> 2, cp = sub & 3;
  float acc[4][2] = {{0.f,0.f},{0.f,0.f},{0.f,0.f},{0.f,0.f}};
  float hprev = 0.f, cprev = 0.f;  // threads 0..31: per-(b,d) recurrent state

  auto gsync = [&]() {
    asm volatile("s_waitcnt vmcnt(0)" ::: "memory");
    __syncthreads();
    ++nbar;
    if (tid == 0)
      __hip_atomic_store(&flags[wg * 16], nbar, __ATOMIC_RELAXED, __HIP_MEMORY_SCOPE_SYSTEM);
    while (__hip_atomic_load(&flags[tid * 16], __ATOMIC_RELAXED, __HIP_MEMORY_SCOPE_SYSTEM) < nbar)
      __builtin_amdgcn_s_sleep(1);
    __syncthreads();
  };

  // ---------------- prologue ----------------
  {
    // ctx_trans = context @ att_ctx_W1 + att_b1 : 4 (b,l)-rows per wg
    for (int j = 0; j < 4; ++j) {
      int rid = wg * 4 + j;  // rid = b*64 + l
      __syncthreads();
      for (int i = tid; i < 512; i += NT) scr[i] = p.ctx[rid * 512 + i];
      __syncthreads();
      float a0 = 0.f, a1 = 0.f, a2 = 0.f, a3 = 0.f;
      for (int c = 0; c < 512; c += 4) {
        a0 += scr[c+0] * p.acW1[(c+0) * 256 + tid];
        a1 += scr[c+1] * p.acW1[(c+1) * 256 + tid];
        a2 += scr[c+2] * p.acW1[(c+2) * 256 + tid];
        a3 += scr[c+3] * p.acW1[(c+3) * 256 + tid];
      }
      bst(wsp + WS_CT + rid * 256 + tid, p.ab1[tid] + ((a0 + a1) + (a2 + a3)));
    }
    __syncthreads();
    // persistent gate-GEMM weights: quarter q, cols (base, base+1); K rows
    // 0..511=Wx, 512..1023=U, 1024..1535=P, 1536..2047=C, 2048..2559=H
    const float* mats[5] = {p.Wx, p.U, p.P, p.C, p.H};
    for (int q = 0; q < 4; ++q) {
      for (int r = tid; r < 2560; r += NT) {
        int m = r >> 9, rr = r & 511;
        vf2 v = *(const vf2*)(mats[m] + rr * 2048 + base + 512 * q);
        *(vf2*)(wt + q * 5140 + r * 2) = v;
      }
    }
    // bf16-packed projection weights, COLUMN-MAJOR [col][k] (distributed, bypass)
    {
      uint32_t* hpd = (uint32_t*)(wsp + WS_HHP);
      for (int idx = wg * NT + tid; idx < 131072; idx += NWG * NT) {
        int col = idx & 255, k = idx >> 8;
        uint32_t lo = f2bf(p.hthW1[k * 256 + col]);
        uint32_t hi = f2bf(p.hhW[k * 256 + col]);
        bstu(hpd + col * 512 + k, lo | (hi << 16));
      }
      uint32_t* ahd = (uint32_t*)(wsp + WS_AHB);
      for (int idx = wg * NT + tid; idx < 65536; idx += NWG * NT) {
        int col = idx & 255, kk = idx >> 8;
        uint32_t lo = f2bf(p.ahW1[(2 * kk) * 256 + col]);
        uint32_t hi = f2bf(p.ahW1[(2 * kk + 1) * 256 + col]);
        bstu(ahd + col * 256 + kk, lo | (hi << 16));
      }
    }
    // att WGs: persistent score vectors
    if (wg < 16)            { av2[tid] = p.aW2[tid]; }
    else if (wg < 32)       { av2[tid] = p.hW2[tid]; abv[tid] = p.hhb[tid]; }
    // stage X(0)
    #pragma unroll
    for (int j = 0; j < 8; ++j) {
      int i4 = tid + j * NT, b = i4 >> 7, k0 = (i4 << 2) & 511;
      vf4 v = *(const vf4*)(p.X + (b * 64 + 0) * 512 + k0);
      *(vf4*)(zs + b * 516 + k0) = v;
    }
    __syncthreads();
  }

  // register-cached weight slices for U (comp 1) and C (comp 3): 64 VGPR each
  vf2 wU[32], wC[32];
  #pragma unroll
  for (int j = 0; j < 32; ++j) {
    int k = kh + (j << 4);
    wU[j] = *(const vf2*)(wt + cp * 5140 + 1 * 1024 + k * 2);
    wC[j] = *(const vf2*)(wt + cp * 5140 + 3 * 1024 + k * 2);
  }

  auto gemm = [&](int comp) {
    const float* wp = wt + cp * 5140 + comp * 1024;
    const float* zb = zs + (bg * 4) * 516;
    #pragma unroll 4
    for (int j = 0; j < 32; ++j) {
      int k = kh + (j << 4);
      vf2 w = *(const vf2*)(wp + k * 2);
      float z0 = zb[k], z1 = zb[516 + k], z2 = zb[1032 + k], z3 = zb[1548 + k];
      acc[0][0] += z0 * w.x; acc[0][1] += z0 * w.y;
      acc[1][0] += z1 * w.x; acc[1][1] += z1 * w.y;
      acc[2][0] += z2 * w.x; acc[2][1] += z2 * w.y;
      acc[3][0] += z3 * w.x; acc[3][1] += z3 * w.y;
    }
  };
  auto gemmR = [&](const vf2* wr) {   // register-operand variant (U/C)
    const float* zb = zs + (bg * 4) * 516;
    #pragma unroll
    for (int j = 0; j < 32; ++j) {
      int k = kh + (j << 4);
      vf2 w = wr[j];
      float z0 = zb[k], z1 = zb[516 + k], z2 = zb[1032 + k], z3 = zb[1548 + k];
      acc[0][0] += z0 * w.x; acc[0][1] += z0 * w.y;
      acc[1][0] += z1 * w.x; acc[1][1] += z1 * w.y;
      acc[2][0] += z2 * w.x; acc[2][1] += z2 * w.y;
      acc[3][0] += z3 * w.x; acc[3][1] += z3 * w.y;
    }
  };

  gemm(0);   // x-part for t=0
  gsync();   // publish CT + packed weights before t=0 attention

  for (int t = 0; t < 64; ++t) {
    // ================= Phase A =================
    // att WGs first (critical path): local bf16 proj + attention -> cv / hc
    if (wg < 32) {
      const int b = wg & 15;
      if (tid < 128) {
        vf4 v = {0.f, 0.f, 0.f, 0.f};
        if (t > 0) v = *(const vf4*)(wsp + WS_HIST + (b * 64 + (t - 1)) * 512 + tid * 4);
        *(vf4*)(hst + tid * 4) = v;
      }
      __syncthreads();
      if (wg < 16) {
        // ---- ctx attention: col-major bf16 stream, vf4 (8 k / load) ----
        const vu4* acol = (const vu4*)((const uint32_t*)(wsp + WS_AHB) + tid * 256);
        float s = 0.f;
        #pragma unroll 8
        for (int i = 0; i < 64; ++i) {
          vu4 pk = acol[i];
          int k0 = i * 8;
          s += hst[k0+0] * bflo(pk.x) + hst[k0+1] * bfhi(pk.x)
             + hst[k0+2] * bflo(pk.y) + hst[k0+3] * bfhi(pk.y)
             + hst[k0+4] * bflo(pk.z) + hst[k0+5] * bfhi(pk.z)
             + hst[k0+6] * bflo(pk.w) + hst[k0+7] * bfhi(pk.w);
        }
        aw[tid] = s;
        __syncthreads();
        {
          int w = tid >> 6, s32 = tid & 31, hi = (tid >> 5) & 1;
          float b2 = *p.ab2;
          for (int l = w * 2 + hi; l < 64; l += 8) {
            float sc = 0.f;
            #pragma unroll
            for (int q = 0; q < 8; ++q) { int a = s32 + (q << 5); sc += av2[a] * tanh_f(wsp[WS_CT + (b * 64 + l) * 256 + a] + aw[a]); }
            sc = hsum32(sc) + b2;
            if (s32 == 0) araw[l] = (p.cmask[b * 64 + l] > 0) ? -INFINITY : sc;
          }
        }
        __syncthreads();
        if (tid < 64) {
          float r = araw[tid];
          float mx = wmax(r);
          float e = __expf(r - mx);
          float sm = wsum(e);
          asmx[tid] = e / sm;
        }
        __syncthreads();
        {
          int db = tid & 127, half = tid >> 7;
          vf4 a0 = {0.f, 0.f, 0.f, 0.f};
          #pragma unroll 4
          for (int l = half; l < 64; l += 2) {
            float ca = asmx[l];
            vf4 cv = *(const vf4*)(p.ctx + (b * 64 + l) * 512 + db * 4);
            a0.x += ca * cv.x; a0.y += ca * cv.y; a0.z += ca * cv.z; a0.w += ca * cv.w;
          }
          *(vf4*)(scr + tid * 4) = a0;
        }
        __syncthreads();
        if (tid < 128) {
          vf4 u = *(vf4*)(scr + tid * 4), v = *(vf4*)(scr + (tid + 128) * 4);
          u.x += v.x; u.y += v.y; u.z += v.z; u.w += v.w;
          bst4(p.out + OUT_CTX + (b * 64 + t) * 512 + tid * 4, u);
        }
      } else {
        // ---- hist attention: col-major packed stream, vf4 (4 k / load) ----
        const vu4* wcol = (const vu4*)((const uint32_t*)(wsp + WS_HHP) + tid * 512);
        float s1 = 0.f, s2 = 0.f;
        #pragma unroll 8
        for (int i = 0; i < 128; ++i) {
          vu4 pk = wcol[i];
          int k0 = i * 4;
          float h0 = hst[k0+0], h1 = hst[k0+1], h2 = hst[k0+2], h3 = hst[k0+3];
          s1 += h0 * bflo(pk.x) + h1 * bflo(pk.y) + h2 * bflo(pk.z) + h3 * bflo(pk.w);
          s2 += h0 * bfhi(pk.x) + h1 * bfhi(pk.y) + h2 * bfhi(pk.z) + h3 * bfhi(pk.w);
        }
        aw[tid] = s1;
        if (t > 0) wsp[WS_CACHE + (b * 64 + (t - 1)) * 256 + tid] = s2;  // same-WG, plain cached
        __syncthreads();
        {
          int w = tid >> 6, s32 = tid & 31, hi = (tid >> 5) & 1;
          float b2 = *p.hb2;
          for (int l = w * 2 + hi; l < t; l += 8) {
            float sc = 0.f;
            #pragma unroll
            for (int q = 0; q < 8; ++q) { int a = s32 + (q << 5); sc += av2[a] * tanh_f(wsp[WS_CACHE + (b * 64 + l) * 256 + a] + abv[a] + aw[a]); }
            sc = hsum32(sc) + b2;
            if (s32 == 0) araw[l] = sc;
          }
          if (tid < 32) {  // raw value of the (zero) unwritten hist rows
            float sc = 0.f;
            #pragma unroll
            for (int q = 0; q < 8; ++q) { int a = tid + (q << 5); sc += av2[a] * tanh_f(abv[a] + aw[a]); }
            sc = hsum32(sc) + b2;
            if (tid == 0) arawZ[0] = sc;
          }
        }
        __syncthreads();
        if (tid < 64) {
          float r = (tid < t) ? araw[tid] : arawZ[0];
          float mx = wmax(r);                    // max over ALL t' (matches reference)
          float e = (tid < t) ? __expf(r - mx) : 0.f;
          float sm = wsum(e);
          asmx[tid] = e / (sm + 1e-7f);
        }
        __syncthreads();
        {
          int db = tid & 127, half = tid >> 7;
          vf4 a0 = {0.f, 0.f, 0.f, 0.f};
          #pragma unroll 4
          for (int l = half; l < t; l += 2) {
            float hv = asmx[l];
            vf4 hvv = *(const vf4*)(wsp + WS_HIST + (b * 64 + l) * 512 + db * 4);
            a0.x += hv * hvv.x; a0.y += hv * hvv.y; a0.z += hv * hvv.z; a0.w += hv * hvv.w;
          }
          *(vf4*)(scr + tid * 4) = a0;
        }
        __syncthreads();
        if (tid < 128) {
          vf4 u = *(vf4*)(scr + tid * 4), v = *(vf4*)(scr + (tid + 128) * 4);
          u.x += v.x; u.y += v.y; u.z += v.z; u.w += v.w;
          bst4(wsp + WS_HC + b * 512 + tid * 4, u);
        }
      }
    }
    // all WGs: gate-GEMM h and par parts
    __syncthreads();
    if (t == 0) {
      vf4 z = {0.f, 0.f, 0.f, 0.f};
      #pragma unroll
      for (int j = 0; j < 8; ++j) {
        int i4 = tid + j * NT, b = i4 >> 7, k0 = (i4 << 2) & 511;
        *(vf4*)(zs + b * 516 + k0) = z;
      }
    } else {
      #pragma unroll
      for (int j = 0; j < 8; ++j) {
        int i4 = tid + j * NT, b = i4 >> 7, k0 = (i4 << 2) & 511;
        vf4 v = *(const vf4*)(wsp + WS_HIST + (b * 64 + (t - 1)) * 512 + k0);
        *(vf4*)(zs + b * 516 + k0) = v;
      }
    }
    __syncthreads();
    gemmR(wU);
    __syncthreads();
    {
      #pragma unroll
      for (int j = 0; j < 8; ++j) {
        int i4 = tid + j * NT, b = i4 >> 7, k0 = (i4 << 2) & 511;
        int par = p.parent[b * 64 + t];
        vf4 v = {0.f, 0.f, 0.f, 0.f};
        if (t > 0 && par < t) v = *(const vf4*)(wsp + WS_HIST + (b * 64 + par) * 512 + k0);
        *(vf4*)(zs + b * 516 + k0) = v;
      }
    }
    __syncthreads();
    gemm(2);
    gsync();   // barrier Y: cv / hc published

    // ================= Phase B =================
    {
      #pragma unroll
      for (int j = 0; j < 8; ++j) {  // stage ctx_vec from out (cached; fresh address each step)
        int i4 = tid + j * NT, b = i4 >> 7, k0 = (i4 << 2) & 511;
        vf4 v = *(const vf4*)(p.out + OUT_CTX + (b * 64 + t) * 512 + k0);
        *(vf4*)(zs + b * 516 + k0) = v;
      }
    }
    __syncthreads();
    // issue HC bypass loads now; drain after gemm(3) so MALL latency hides
    vf4 rhc[8];
    {
      const float* q[8];
      #pragma unroll
      for (int j = 0; j < 8; ++j) { int i4 = tid + j * NT; q[j] = wsp + WS_HC + (i4 >> 7) * 512 + ((i4 << 2) & 511); }
      bld8_issue(rhc, q[0], q[1], q[2], q[3], q[4], q[5], q[6], q[7]);
    }
    gemmR(wC);
    __syncthreads();
    bwait8(rhc);
    #pragma unroll
    for (int j = 0; j < 8; ++j) { int i4 = tid + j * NT; *(vf4*)(zs + (i4 >> 7) * 516 + ((i4 << 2) & 511)) = rhc[j]; }
    __syncthreads();
    gemm(4);
    {
      float* s8 = scr + (kh * 16 + sub) * 8;
      #pragma unroll
      for (int i = 0; i < 4; ++i) { s8[i*2] = acc[i][0]; s8[i*2+1] = acc[i][1]; acc[i][0] = 0.f; acc[i][1] = 0.f; }
    }
    __syncthreads();
    if (t < 63) {
      #pragma unroll
      for (int j = 0; j < 8; ++j) {  // pre-stage X(t+1)
        int i4 = tid + j * NT, b = i4 >> 7, k0 = (i4 << 2) & 511;
        vf4 v = *(const vf4*)(p.X + (b * 64 + (t + 1)) * 512 + k0);
        *(vf4*)(zs + b * 516 + k0) = v;
      }
    }
    if (tid < 128) {
      int b = tid >> 3, c = tid & 7;  // c = quarter*2 + coloff
      int n = base + (c & 1) + 512 * (c >> 1);
      float g = p.bx[n];
      int sidx = (b >> 2) * 4 + (c >> 1);
      int aidx = (b & 3) * 2 + (c & 1);
      #pragma unroll
      for (int k2 = 0; k2 < 16; ++k2) g += scr[(k2 * 16 + sidx) * 8 + aidx];
      gld[b * 8 + c] = g;
    }
    __syncthreads();
    if (tid < 32) {
      int b = tid >> 1, dj = tid & 1;
      int d = base + dj;
      float gi = gld[b*8 + 0 + dj];
      float gf = gld[b*8 + 2 + dj];
      float gg = gld[b*8 + 4 + dj];
      float go = gld[b*8 + 6 + dj];
      float i_ = sigm_f(gi), f_ = sigm_f(gf), o_ = sigm_f(go);
      float cn = f_ * cprev + i_ * tanh_f(gg);
      float hn = o_ * tanh_f(cn);
      float m_ = p.mask[b * 64 + t];
      hn = (1.f - m_) * hprev + m_ * hn;
      cn = (1.f - m_) * cprev + m_ * cn;
      hprev = hn; cprev = cn;
      bst(wsp + WS_HIST + (b * 64 + t) * 512 + d, hn);
      p.out[OUT_HS + (b * 64 + t) * 512 + d] = hn;
      p.out[OUT_CS + (b * 64 + t) * 512 + d] = cn;
    }
    if (t < 63) {
      gemm(0);   // x-part for t+1 (zs holds X(t+1))
      gsync();   // barrier X: h(t) published
    }
  }
}

extern "C" void kernel_launch(void* const* d_in, const int* in_sizes, int n_in,
                              void* d_out, int out_size, void* d_ws, size_t ws_size,
                              hipStream_t stream) {
  CAParams p;
  p.X      = (const float*)d_in[0];
  p.ctx    = (const float*)d_in[1];
  p.parent = (const int*)  d_in[2];
  p.cmask  = (const int*)  d_in[3];
  p.mask   = (const float*)d_in[4];
  p.Wx = (const float*)d_in[5];  p.bx = (const float*)d_in[6];
  p.U  = (const float*)d_in[7];  p.C  = (const float*)d_in[8];
  p.P  = (const float*)d_in[9];  p.H  = (const float*)d_in[10];
  p.acW1 = (const float*)d_in[11]; p.ab1 = (const float*)d_in[12];
  p.ahW1 = (const float*)d_in[13]; p.aW2 = (const float*)d_in[14]; p.ab2 = (const float*)d_in[15];
  p.hhW  = (const float*)d_in[16]; p.hhb = (const float*)d_in[17];
  p.hthW1= (const float*)d_in[18]; p.hW2 = (const float*)d_in[19]; p.hb2 = (const float*)d_in[20];
  p.out = (float*)d_out;
  p.ws  = (float*)d_ws;

  // reset barrier flags (nbar restarts at 1 each launch)
  (void)hipMemsetAsync(d_ws, 0, 16384, stream);

  static_assert(LDS_FLOATS * 4 <= 160 * 1024, "LDS budget");
  (void)hipFuncSetAttribute((const void*)condatt_kernel,
                      hipFuncAttributeMaxDynamicSharedMemorySize, LDS_FLOATS * 4);
  hipLaunchKernelGGL(condatt_kernel, dim3(NWG), dim3(NT), LDS_FLOATS * 4, stream, p);
}

// Round 12
// 2122.079 us; speedup vs baseline: 1.4707x; 1.4707x over previous
//
#include <hip/hip_runtime.h>
#include <cmath>
#include <cstdint>

#define NWG 256
#define NT  256

// dims: B=16, T=64, L=64, D=512, A=256, 4D=2048
// ws float offsets
#define WS_FLAGS 0         // u32 flags[256][16]: w0 = gsync (16 KB)
#define WS_HC    8192      // 16*512   (h_ctx, rewritten per step; bypass-only)
#define WS_CT    16384     // 16*64*256 ctx_trans (write-once prologue, cached reads)
#define WS_CACHE 278528    // 16*64*256 hist proj rows (same-WG write+read, plain cached)
#define WS_HIST  540672    // 16*64*512 h history rows (write-once per row; bypass write / cached reads)
#define WS_HHP   1064960   // 512*256 u32: packed (bf16 hthW1 | bf16 hhW<<16) (write-once)
#define WS_AHB   1196032   // 512*128 u32: bf16 ahW1 col-pairs (write-once)
// end: 1261568 floats = 4.82 MB

// out float offsets (hs | cs | ctxs)
#define OUT_HS  0
#define OUT_CS  524288
#define OUT_CTX 1048576

// lds float offsets
#define LDS_WT   0        // 4 quarters x 5140 (2560 K rows * 2 cols interleaved + pad; cp banks 0/20/8/28 distinct)
#define LDS_ZS   20560    // z-stage [16 b][516]
#define LDS_SCR  28816    // scratch 2048 (gemm reduce / einsum partials / prologue)
#define LDS_GLD  30864    // g lds 16*8
#define LDS_ATT  30992    // aw 256 | av2 256 | abv 256 | araw 64 | asmx 64 | arawZ 64 | hst 512
#define LDS_FLOATS 32464  // *4 = 129,856 B < 160 KB

typedef float vf4 __attribute__((ext_vector_type(4)));
typedef float vf2 __attribute__((ext_vector_type(2)));

struct CAParams {
  const float* X; const float* ctx; const int* parent; const int* cmask; const float* mask;
  const float* Wx; const float* bx; const float* U; const float* C; const float* P; const float* H;
  const float* acW1; const float* ab1; const float* ahW1; const float* aW2; const float* ab2;
  const float* hhW; const float* hhb; const float* hthW1; const float* hW2; const float* hb2;
  float* out; float* ws;
};

__device__ __forceinline__ float tanh_f(float x) {
  x = fminf(15.f, fmaxf(-15.f, x));
  float e = __expf(2.f * x);
  return (e - 1.f) / (e + 1.f);
}
__device__ __forceinline__ float sigm_f(float x) { return 1.f / (1.f + __expf(-x)); }
__device__ __forceinline__ float wsum(float v) {
  #pragma unroll
  for (int m = 32; m; m >>= 1) v += __shfl_xor(v, m, 64);
  return v;
}
__device__ __forceinline__ float wmax(float v) {
  #pragma unroll
  for (int m = 32; m; m >>= 1) v = fmaxf(v, __shfl_xor(v, m, 64));
  return v;
}
__device__ __forceinline__ float hsum32(float v) {  // reduce within 32-lane half
  #pragma unroll
  for (int m = 16; m; m >>= 1) v += __shfl_xor(v, m, 64);
  return v;
}
// bf16 round-to-nearest-even
__device__ __forceinline__ uint32_t f2bf(float f) {
  uint32_t u = __float_as_uint(f);
  return (u + 0x7FFFu + ((u >> 16) & 1u)) >> 16;
}

// ---- MALL-coherent bypass ops (sc0 sc1), non-atomic so they pipeline ----
__device__ __forceinline__ void bst(float* a, float v) {
  asm volatile("global_store_dword %0, %1, off sc0 sc1" :: "v"(a), "v"(v) : "memory");
}
__device__ __forceinline__ void bstu(uint32_t* a, uint32_t v) {
  asm volatile("global_store_dword %0, %1, off sc0 sc1" :: "v"(a), "v"(v) : "memory");
}
__device__ __forceinline__ void bst4(float* a, vf4 v) {
  asm volatile("global_store_dwordx4 %0, %1, off sc0 sc1" :: "v"(a), "v"(v) : "memory");
}
// issue-only 8-deep bypass loads; pair with bwait8 (data-dep via +v prevents hoisting)
__device__ __forceinline__ void bld8_issue(vf4* r, const float* q0, const float* q1, const float* q2, const float* q3,
                                           const float* q4, const float* q5, const float* q6, const float* q7) {
  asm volatile(
    "global_load_dwordx4 %0, %8, off sc0 sc1\n"
    "global_load_dwordx4 %1, %9, off sc0 sc1\n"
    "global_load_dwordx4 %2, %10, off sc0 sc1\n"
    "global_load_dwordx4 %3, %11, off sc0 sc1\n"
    "global_load_dwordx4 %4, %12, off sc0 sc1\n"
    "global_load_dwordx4 %5, %13, off sc0 sc1\n"
    "global_load_dwordx4 %6, %14, off sc0 sc1\n"
    "global_load_dwordx4 %7, %15, off sc0 sc1"
    : "=&v"(r[0]),"=&v"(r[1]),"=&v"(r[2]),"=&v"(r[3]),"=&v"(r[4]),"=&v"(r[5]),"=&v"(r[6]),"=&v"(r[7])
    : "v"(q0),"v"(q1),"v"(q2),"v"(q3),"v"(q4),"v"(q5),"v"(q6),"v"(q7)
    : "memory");
}
__device__ __forceinline__ void bwait8(vf4* r) {
  asm volatile("s_waitcnt vmcnt(0)"
    : "+v"(r[0]),"+v"(r[1]),"+v"(r[2]),"+v"(r[3]),"+v"(r[4]),"+v"(r[5]),"+v"(r[6]),"+v"(r[7])
    :: "memory");
}

__global__ void __launch_bounds__(NT, 1) condatt_kernel(CAParams p) {
  extern __shared__ float lds[];
  float* wt   = lds + LDS_WT;
  float* zs   = lds + LDS_ZS;
  float* scr  = lds + LDS_SCR;
  float* gld  = lds + LDS_GLD;
  float* aw   = lds + LDS_ATT;
  float* av2  = lds + LDS_ATT + 256;
  float* abv  = lds + LDS_ATT + 512;
  float* araw = lds + LDS_ATT + 768;
  float* asmx = lds + LDS_ATT + 832;
  float* arawZ= lds + LDS_ATT + 896;
  float* hst  = lds + LDS_ATT + 960;   // 512

  const int tid = threadIdx.x;
  const int wg  = blockIdx.x;
  float* wsp = p.ws;
  unsigned* flags = (unsigned*)wsp;    // 64B-strided flags, one line per WG
  unsigned nbar = 0;

  // XCD-contiguous column assignment (wg%8 = XCD): co-resident WGs own
  // contiguous column blocks -> weight cache lines fully consumed per XCD.
  const int base = 2 * ((wg & 7) * 32 + (wg >> 3));  // gate col pair {base, base+1}

  // discard stale L1/L2 lines from previous dispatch/poison blit
  __threadfence_system();

  const int kh = tid >> 4, sub = tid & 15, bg = sub >> 2, cp = sub & 3;
  float acc[4][2] = {{0.f,0.f},{0.f,0.f},{0.f,0.f},{0.f,0.f}};
  float hprev = 0.f, cprev = 0.f;  // threads 0..31: per-(b,d) recurrent state

  // Flag-array grid barrier: per-WG flag on its own 64B line (parallel stores,
  // parallel polls, no RMW serialization, no cache maintenance).
  auto gsync = [&]() {
    asm volatile("s_waitcnt vmcnt(0)" ::: "memory");
    __syncthreads();
    ++nbar;
    if (tid == 0)
      __hip_atomic_store(&flags[wg * 16], nbar, __ATOMIC_RELAXED, __HIP_MEMORY_SCOPE_SYSTEM);
    while (__hip_atomic_load(&flags[tid * 16], __ATOMIC_RELAXED, __HIP_MEMORY_SCOPE_SYSTEM) < nbar)
      __builtin_amdgcn_s_sleep(1);
    __syncthreads();
  };

  // ---------------- prologue ----------------
  {
    // ctx_trans = context @ att_ctx_W1 + att_b1 : 4 (b,l)-rows per wg
    for (int j = 0; j < 4; ++j) {
      int rid = wg * 4 + j;  // rid = b*64 + l
      __syncthreads();
      for (int i = tid; i < 512; i += NT) scr[i] = p.ctx[rid * 512 + i];
      __syncthreads();
      float a0 = 0.f, a1 = 0.f, a2 = 0.f, a3 = 0.f;
      for (int c = 0; c < 512; c += 4) {
        a0 += scr[c+0] * p.acW1[(c+0) * 256 + tid];
        a1 += scr[c+1] * p.acW1[(c+1) * 256 + tid];
        a2 += scr[c+2] * p.acW1[(c+2) * 256 + tid];
        a3 += scr[c+3] * p.acW1[(c+3) * 256 + tid];
      }
      bst(wsp + WS_CT + rid * 256 + tid, p.ab1[tid] + ((a0 + a1) + (a2 + a3)));
    }
    __syncthreads();
    // persistent gate-GEMM weights: quarter q, cols (base, base+1); K rows
    // 0..511=Wx, 512..1023=U, 1024..1535=P, 1536..2047=C, 2048..2559=H
    const float* mats[5] = {p.Wx, p.U, p.P, p.C, p.H};
    for (int q = 0; q < 4; ++q) {
      for (int r = tid; r < 2560; r += NT) {
        int m = r >> 9, rr = r & 511;
        vf2 v = *(const vf2*)(mats[m] + rr * 2048 + base + 512 * q);
        *(vf2*)(wt + q * 5140 + r * 2) = v;
      }
    }
    // bf16-packed projection weights (distributed build, bypass-published):
    // hh_pack[i] = bf16(hthW1[i]) | bf16(hhW[i])<<16 ; ah_bf = bf16(ahW1) pairs
    {
      uint32_t* hpd = (uint32_t*)(wsp + WS_HHP);
      for (int i = wg * NT + tid; i < 131072; i += NWG * NT) {
        uint32_t lo = f2bf(p.hthW1[i]);
        uint32_t hi = f2bf(p.hhW[i]);
        bstu(hpd + i, lo | (hi << 16));
      }
      uint32_t* ahd = (uint32_t*)(wsp + WS_AHB);
      for (int j = wg * NT + tid; j < 65536; j += NWG * NT) {
        uint32_t lo = f2bf(p.ahW1[j * 2]);
        uint32_t hi = f2bf(p.ahW1[j * 2 + 1]);
        bstu(ahd + j, lo | (hi << 16));
      }
    }
    // att WGs: persistent score vectors
    if (wg < 16)            { av2[tid] = p.aW2[tid]; }
    else if (wg < 32)       { av2[tid] = p.hW2[tid]; abv[tid] = p.hhb[tid]; }
    // stage X(0) and do the x-part GEMM before the loop
    #pragma unroll
    for (int j = 0; j < 8; ++j) {
      int i4 = tid + j * NT, b = i4 >> 7, k0 = (i4 << 2) & 511;
      vf4 v = *(const vf4*)(p.X + (b * 64 + 0) * 512 + k0);
      *(vf4*)(zs + b * 516 + k0) = v;
    }
    __syncthreads();
  }

  auto gemm = [&](int comp) {
    const float* wp = wt + cp * 5140 + comp * 1024;
    const float* zb = zs + (bg * 4) * 516;
    #pragma unroll 4
    for (int j = 0; j < 32; ++j) {
      int k = kh + (j << 4);
      vf2 w = *(const vf2*)(wp + k * 2);
      float z0 = zb[k], z1 = zb[516 + k], z2 = zb[1032 + k], z3 = zb[1548 + k];
      acc[0][0] += z0 * w.x; acc[0][1] += z0 * w.y;
      acc[1][0] += z1 * w.x; acc[1][1] += z1 * w.y;
      acc[2][0] += z2 * w.x; acc[2][1] += z2 * w.y;
      acc[3][0] += z3 * w.x; acc[3][1] += z3 * w.y;
    }
  };

  gemm(0);   // x-part for t=0
  gsync();   // publish CT + packed weights before t=0 attention

  for (int t = 0; t < 64; ++t) {
    // ================= Phase A =================
    // att WGs first (critical path): local bf16 proj + attention -> cv / hc
    if (wg < 32) {
      const int b = wg & 15;
      if (tid < 128) {
        vf4 v = {0.f, 0.f, 0.f, 0.f};
        if (t > 0) v = *(const vf4*)(wsp + WS_HIST + (b * 64 + (t - 1)) * 512 + tid * 4);
        *(vf4*)(hst + tid * 4) = v;
      }
      __syncthreads();
      if (wg < 16) {
        // ---- ctx attention ----
        const uint16_t* ahb = (const uint16_t*)(wsp + WS_AHB);
        float s = 0.f;
        #pragma unroll 8
        for (int k = 0; k < 512; ++k)
          s += hst[k] * __uint_as_float((uint32_t)ahb[k * 256 + tid] << 16);
        aw[tid] = s;
        __syncthreads();
        {
          int w = tid >> 6, s32 = tid & 31, hi = (tid >> 5) & 1;
          float b2 = *p.ab2;
          for (int l = w * 2 + hi; l < 64; l += 8) {
            float sc = 0.f;
            #pragma unroll
            for (int q = 0; q < 8; ++q) { int a = s32 + (q << 5); sc += av2[a] * tanh_f(wsp[WS_CT + (b * 64 + l) * 256 + a] + aw[a]); }
            sc = hsum32(sc) + b2;
            if (s32 == 0) araw[l] = (p.cmask[b * 64 + l] > 0) ? -INFINITY : sc;
          }
        }
        __syncthreads();
        if (tid < 64) {
          float r = araw[tid];
          float mx = wmax(r);
          float e = __expf(r - mx);
          float sm = wsum(e);
          asmx[tid] = e / sm;
        }
        __syncthreads();
        {
          int db = tid & 127, half = tid >> 7;
          vf4 a0 = {0.f, 0.f, 0.f, 0.f};
          #pragma unroll 4
          for (int l = half; l < 64; l += 2) {
            float ca = asmx[l];
            vf4 cv = *(const vf4*)(p.ctx + (b * 64 + l) * 512 + db * 4);
            a0.x += ca * cv.x; a0.y += ca * cv.y; a0.z += ca * cv.z; a0.w += ca * cv.w;
          }
          *(vf4*)(scr + tid * 4) = a0;
        }
        __syncthreads();
        if (tid < 128) {
          vf4 u = *(vf4*)(scr + tid * 4), v = *(vf4*)(scr + (tid + 128) * 4);
          u.x += v.x; u.y += v.y; u.z += v.z; u.w += v.w;
          bst4(p.out + OUT_CTX + (b * 64 + t) * 512 + tid * 4, u);
        }
      } else {
        // ---- hist attention ----
        const uint32_t* hp = (const uint32_t*)(wsp + WS_HHP);
        float s1 = 0.f, s2 = 0.f;
        #pragma unroll 8
        for (int k = 0; k < 512; ++k) {
          uint32_t pk = hp[k * 256 + tid];
          float hv = hst[k];
          s1 += hv * __uint_as_float(pk << 16);
          s2 += hv * __uint_as_float(pk & 0xFFFF0000u);
        }
        aw[tid] = s1;
        if (t > 0) wsp[WS_CACHE + (b * 64 + (t - 1)) * 256 + tid] = s2;  // same-WG, plain cached
        __syncthreads();
        {
          int w = tid >> 6, s32 = tid & 31, hi = (tid >> 5) & 1;
          float b2 = *p.hb2;
          for (int l = w * 2 + hi; l < t; l += 8) {
            float sc = 0.f;
            #pragma unroll
            for (int q = 0; q < 8; ++q) { int a = s32 + (q << 5); sc += av2[a] * tanh_f(wsp[WS_CACHE + (b * 64 + l) * 256 + a] + abv[a] + aw[a]); }
            sc = hsum32(sc) + b2;
            if (s32 == 0) araw[l] = sc;
          }
          if (tid < 32) {  // raw value of the (zero) unwritten hist rows
            float sc = 0.f;
            #pragma unroll
            for (int q = 0; q < 8; ++q) { int a = tid + (q << 5); sc += av2[a] * tanh_f(abv[a] + aw[a]); }
            sc = hsum32(sc) + b2;
            if (tid == 0) arawZ[0] = sc;
          }
        }
        __syncthreads();
        if (tid < 64) {
          float r = (tid < t) ? araw[tid] : arawZ[0];
          float mx = wmax(r);                    // max over ALL t' (matches reference)
          float e = (tid < t) ? __expf(r - mx) : 0.f;
          float sm = wsum(e);
          asmx[tid] = e / (sm + 1e-7f);
        }
        __syncthreads();
        {
          int db = tid & 127, half = tid >> 7;
          vf4 a0 = {0.f, 0.f, 0.f, 0.f};
          #pragma unroll 4
          for (int l = half; l < t; l += 2) {
            float hv = asmx[l];
            vf4 hvv = *(const vf4*)(wsp + WS_HIST + (b * 64 + l) * 512 + db * 4);
            a0.x += hv * hvv.x; a0.y += hv * hvv.y; a0.z += hv * hvv.z; a0.w += hv * hvv.w;
          }
          *(vf4*)(scr + tid * 4) = a0;
        }
        __syncthreads();
        if (tid < 128) {
          vf4 u = *(vf4*)(scr + tid * 4), v = *(vf4*)(scr + (tid + 128) * 4);
          u.x += v.x; u.y += v.y; u.z += v.z; u.w += v.w;
          bst4(wsp + WS_HC + b * 512 + tid * 4, u);
        }
      }
    }
    // all WGs: gate-GEMM h and par parts
    __syncthreads();
    if (t == 0) {
      vf4 z = {0.f, 0.f, 0.f, 0.f};
      #pragma unroll
      for (int j = 0; j < 8; ++j) {
        int i4 = tid + j * NT, b = i4 >> 7, k0 = (i4 << 2) & 511;
        *(vf4*)(zs + b * 516 + k0) = z;
      }
    } else {
      #pragma unroll
      for (int j = 0; j < 8; ++j) {
        int i4 = tid + j * NT, b = i4 >> 7, k0 = (i4 << 2) & 511;
        vf4 v = *(const vf4*)(wsp + WS_HIST + (b * 64 + (t - 1)) * 512 + k0);
        *(vf4*)(zs + b * 516 + k0) = v;
      }
    }
    __syncthreads();
    gemm(1);
    __syncthreads();
    {
      #pragma unroll
      for (int j = 0; j < 8; ++j) {
        int i4 = tid + j * NT, b = i4 >> 7, k0 = (i4 << 2) & 511;
        int par = p.parent[b * 64 + t];
        vf4 v = {0.f, 0.f, 0.f, 0.f};
        if (t > 0 && par < t) v = *(const vf4*)(wsp + WS_HIST + (b * 64 + par) * 512 + k0);
        *(vf4*)(zs + b * 516 + k0) = v;
      }
    }
    __syncthreads();
    gemm(2);
    gsync();   // barrier Y: cv / hc published

    // ================= Phase B =================
    {
      #pragma unroll
      for (int j = 0; j < 8; ++j) {  // stage ctx_vec from out (cached; fresh address each step)
        int i4 = tid + j * NT, b = i4 >> 7, k0 = (i4 << 2) & 511;
        vf4 v = *(const vf4*)(p.out + OUT_CTX + (b * 64 + t) * 512 + k0);
        *(vf4*)(zs + b * 516 + k0) = v;
      }
    }
    __syncthreads();
    // issue HC bypass loads now; drain after gemm(3) so MALL latency hides
    vf4 rhc[8];
    {
      const float* q[8];
      #pragma unroll
      for (int j = 0; j < 8; ++j) { int i4 = tid + j * NT; q[j] = wsp + WS_HC + (i4 >> 7) * 512 + ((i4 << 2) & 511); }
      bld8_issue(rhc, q[0], q[1], q[2], q[3], q[4], q[5], q[6], q[7]);
    }
    gemm(3);
    __syncthreads();
    bwait8(rhc);
    #pragma unroll
    for (int j = 0; j < 8; ++j) { int i4 = tid + j * NT; *(vf4*)(zs + (i4 >> 7) * 516 + ((i4 << 2) & 511)) = rhc[j]; }
    __syncthreads();
    gemm(4);
    {
      float* s8 = scr + (kh * 16 + sub) * 8;
      #pragma unroll
      for (int i = 0; i < 4; ++i) { s8[i*2] = acc[i][0]; s8[i*2+1] = acc[i][1]; acc[i][0] = 0.f; acc[i][1] = 0.f; }
    }
    __syncthreads();
    if (t < 63) {
      #pragma unroll
      for (int j = 0; j < 8; ++j) {  // pre-stage X(t+1)
        int i4 = tid + j * NT, b = i4 >> 7, k0 = (i4 << 2) & 511;
        vf4 v = *(const vf4*)(p.X + (b * 64 + (t + 1)) * 512 + k0);
        *(vf4*)(zs + b * 516 + k0) = v;
      }
    }
    if (tid < 128) {
      int b = tid >> 3, c = tid & 7;  // c = quarter*2 + coloff
      int n = base + (c & 1) + 512 * (c >> 1);
      float g = p.bx[n];
      int sidx = (b >> 2) * 4 + (c >> 1);
      int aidx = (b & 3) * 2 + (c & 1);
      #pragma unroll
      for (int k2 = 0; k2 < 16; ++k2) g += scr[(k2 * 16 + sidx) * 8 + aidx];
      gld[b * 8 + c] = g;
    }
    __syncthreads();
    if (tid < 32) {
      int b = tid >> 1, dj = tid & 1;
      int d = base + dj;
      float gi = gld[b*8 + 0 + dj];
      float gf = gld[b*8 + 2 + dj];
      float gg = gld[b*8 + 4 + dj];
      float go = gld[b*8 + 6 + dj];
      float i_ = sigm_f(gi), f_ = sigm_f(gf), o_ = sigm_f(go);
      float cn = f_ * cprev + i_ * tanh_f(gg);
      float hn = o_ * tanh_f(cn);
      float m_ = p.mask[b * 64 + t];
      hn = (1.f - m_) * hprev + m_ * hn;
      cn = (1.f - m_) * cprev + m_ * cn;
      hprev = hn; cprev = cn;
      bst(wsp + WS_HIST + (b * 64 + t) * 512 + d, hn);
      p.out[OUT_HS + (b * 64 + t) * 512 + d] = hn;
      p.out[OUT_CS + (b * 64 + t) * 512 + d] = cn;
    }
    if (t < 63) {
      gemm(0);   // x-part for t+1 (zs holds X(t+1))
      gsync();   // barrier X: h(t) published
    }
  }
}

extern "C" void kernel_launch(void* const* d_in, const int* in_sizes, int n_in,
                              void* d_out, int out_size, void* d_ws, size_t ws_size,
                              hipStream_t stream) {
  CAParams p;
  p.X      = (const float*)d_in[0];
  p.ctx    = (const float*)d_in[1];
  p.parent = (const int*)  d_in[2];
  p.cmask  = (const int*)  d_in[3];
  p.mask   = (const float*)d_in[4];
  p.Wx = (const float*)d_in[5];  p.bx = (const float*)d_in[6];
  p.U  = (const float*)d_in[7];  p.C  = (const float*)d_in[8];
  p.P  = (const float*)d_in[9];  p.H  = (const float*)d_in[10];
  p.acW1 = (const float*)d_in[11]; p.ab1 = (const float*)d_in[12];
  p.ahW1 = (const float*)d_in[13]; p.aW2 = (const float*)d_in[14]; p.ab2 = (const float*)d_in[15];
  p.hhW  = (const float*)d_in[16]; p.hhb = (const float*)d_in[17];
  p.hthW1= (const float*)d_in[18]; p.hW2 = (const float*)d_in[19]; p.hb2 = (const float*)d_in[20];
  p.out = (float*)d_out;
  p.ws  = (float*)d_ws;

  // reset barrier flags (nbar restarts at 1 each launch)
  (void)hipMemsetAsync(d_ws, 0, 16384, stream);

  static_assert(LDS_FLOATS * 4 <= 160 * 1024, "LDS budget");
  (void)hipFuncSetAttribute((const void*)condatt_kernel,
                      hipFuncAttributeMaxDynamicSharedMemorySize, LDS_FLOATS * 4);
  hipLaunchKernelGGL(condatt_kernel, dim3(NWG), dim3(NT), LDS_FLOATS * 4, stream, p);
}